// Round 2
// baseline (3509.831 us; speedup 1.0000x reference)
//
#include <hip/hip_runtime.h>
#include <hip/hip_bf16.h>

#define NPIX 65536
#define CDIM 192
#define C2   384
#define HEADS 4
#define HD   48

// ---------------------------------------------------------------------------
// 1x1 conv as GEMM: Out[oc][n] = sum_c W[wRowOff+oc][c] * X[c][n], oc<ocValid.
// Tile: 64 oc x 128 pix, K-chunks of 32. Rows >= ocValid masked (zero weights,
// stores skipped) so OC=48 head-chunks work with the 64-row tile.
// ---------------------------------------------------------------------------
__global__ __launch_bounds__(256) void gemm1x1_kernel(
    const float* __restrict__ X, const float* __restrict__ Wt,
    float* __restrict__ Out, int Cin, int ocValid, int wRowOff) {
  const int n0 = blockIdx.x * 128;
  const int m0 = blockIdx.y * 64;

  __shared__ float sX[32][128];    // 16 KB
  __shared__ float sW[32][68];     // transposed W tile, padded (8.5 KB)

  const int t = threadIdx.x;
  const int tx = t & 15;           // pixel group (8 px)
  const int ty = t >> 4;           // oc group (4 oc)

  float acc[4][8];
#pragma unroll
  for (int i = 0; i < 4; ++i)
#pragma unroll
    for (int j = 0; j < 8; ++j) acc[i][j] = 0.f;

  for (int k0 = 0; k0 < Cin; k0 += 32) {
    // stage X tile 32x128 (float4, coalesced)
#pragma unroll
    for (int it = 0; it < 4; ++it) {
      int e = t * 4 + it * 1024;
      int kk = e >> 7, col = e & 127;
      *(float4*)&sX[kk][col] =
          *(const float4*)&X[(size_t)(k0 + kk) * NPIX + n0 + col];
    }
    // stage W tile 64x32 -> transposed sW[kk][m], masked beyond ocValid
#pragma unroll
    for (int it = 0; it < 2; ++it) {
      int e = t * 4 + it * 1024;
      int m = e >> 5, kk = e & 31;
      float4 wv = make_float4(0.f, 0.f, 0.f, 0.f);
      if (m0 + m < ocValid)
        wv = *(const float4*)&Wt[(size_t)(wRowOff + m0 + m) * Cin + k0 + kk];
      sW[kk + 0][m] = wv.x;
      sW[kk + 1][m] = wv.y;
      sW[kk + 2][m] = wv.z;
      sW[kk + 3][m] = wv.w;
    }
    __syncthreads();
#pragma unroll
    for (int kk = 0; kk < 32; ++kk) {
      float xv[8], wv[4];
      *(float4*)&xv[0] = *(float4*)&sX[kk][tx * 8];
      *(float4*)&xv[4] = *(float4*)&sX[kk][tx * 8 + 4];
      *(float4*)&wv[0] = *(float4*)&sW[kk][ty * 4];
#pragma unroll
      for (int i = 0; i < 4; ++i)
#pragma unroll
        for (int j = 0; j < 8; ++j) acc[i][j] += wv[i] * xv[j];
    }
    __syncthreads();
  }
#pragma unroll
  for (int i = 0; i < 4; ++i) {
    if (m0 + ty * 4 + i < ocValid) {
      size_t row = (size_t)(m0 + ty * 4 + i) * NPIX + n0 + tx * 8;
      *(float4*)&Out[row]     = make_float4(acc[i][0], acc[i][1], acc[i][2], acc[i][3]);
      *(float4*)&Out[row + 4] = make_float4(acc[i][4], acc[i][5], acc[i][6], acc[i][7]);
    }
  }
}

// ---------------------------------------------------------------------------
// depthwise 3x3, pad 1, on a 96-channel chunk (48 q-ch + 48 k-ch of one head).
// Channel c<48 uses dw row (qoff+c); c>=48 uses (koff+c-48).
// ---------------------------------------------------------------------------
__global__ __launch_bounds__(256) void dwconv96_kernel(
    const float* __restrict__ in, const float* __restrict__ dw,
    float* __restrict__ out, int qoff, int koff) {
  int idx = blockIdx.x * 256 + threadIdx.x;   // 96*65536 total
  int wcol = idx & 255;
  int hrow = (idx >> 8) & 255;
  int c = idx >> 16;                           // 0..95
  int wrow = (c < HD) ? (qoff + c) : (koff + c - HD);
  const float* ip = in + (size_t)c * NPIX;
  const float* wp = dw + wrow * 9;
  float s = 0.f;
#pragma unroll
  for (int r = -1; r <= 1; ++r) {
    int hh = hrow + r;
    if ((unsigned)hh < 256u) {
#pragma unroll
      for (int cc = -1; cc <= 1; ++cc) {
        int ww = wcol + cc;
        if ((unsigned)ww < 256u)
          s += wp[(r + 1) * 3 + (cc + 1)] * ip[hh * 256 + ww];
      }
    }
  }
  out[idx] = s;
}

// ---------------------------------------------------------------------------
// per-channel spatial L2 norm of the 96-channel dw output chunk.
// norms index: c<48 -> nqoff+c (q), else nkoff+c-48 (k).
// ---------------------------------------------------------------------------
__global__ __launch_bounds__(256) void norm96_kernel(
    const float* __restrict__ qkdw, float* __restrict__ norms,
    int nqoff, int nkoff) {
  int ch = blockIdx.x;                  // 0..95
  const float* p = qkdw + (size_t)ch * NPIX;
  int t = threadIdx.x;
  float s = 0.f;
  for (int i = t * 4; i < NPIX; i += 1024) {
    float4 v = *(const float4*)&p[i];
    s += v.x * v.x + v.y * v.y + v.z * v.z + v.w * v.w;
  }
#pragma unroll
  for (int off = 32; off > 0; off >>= 1) s += __shfl_down(s, off);
  __shared__ float red[4];
  if ((t & 63) == 0) red[t >> 6] = s;
  __syncthreads();
  if (t == 0) {
    int g = (ch < HD) ? (nqoff + ch) : (nkoff + ch - HD);
    norms[g] = sqrtf(red[0] + red[1] + red[2] + red[3]);
  }
}

// ---------------------------------------------------------------------------
// Gram partials: 48x48 q.k dots over a 512-px spatial split. No atomics:
// each of 128 splits writes its own [48][48] slice (deterministic).
// qkdw layout: rows 0-47 = q, rows 48-95 = k.
// ---------------------------------------------------------------------------
__global__ __launch_bounds__(256) void gram_partial_kernel(
    const float* __restrict__ qkdw, float* __restrict__ partials) {
  const int split = blockIdx.x;       // 128
  const float* qp = qkdw;
  const float* kp = qkdw + (size_t)HD * NPIX;

  __shared__ float sQ[48][132];
  __shared__ float sK[48][132];

  const int t = threadIdx.x;
  const int i0 = (t & 15) * 3;
  const int j0 = (t >> 4) * 3;
  float acc[3][3];
#pragma unroll
  for (int a = 0; a < 3; ++a)
#pragma unroll
    for (int c = 0; c < 3; ++c) acc[a][c] = 0.f;

  for (int sub = 0; sub < 4; ++sub) {
    int nb = split * 512 + sub * 128;
    for (int e = t * 4; e < 48 * 128; e += 1024) {
      int row = e >> 7, col = e & 127;
      *(float4*)&sQ[row][col] = *(const float4*)&qp[(size_t)row * NPIX + nb + col];
      *(float4*)&sK[row][col] = *(const float4*)&kp[(size_t)row * NPIX + nb + col];
    }
    __syncthreads();
#pragma unroll 8
    for (int nn = 0; nn < 128; ++nn) {
      float qv[3], kv[3];
#pragma unroll
      for (int a = 0; a < 3; ++a) qv[a] = sQ[i0 + a][nn];
#pragma unroll
      for (int c = 0; c < 3; ++c) kv[c] = sK[j0 + c][nn];
#pragma unroll
      for (int a = 0; a < 3; ++a)
#pragma unroll
        for (int c = 0; c < 3; ++c) acc[a][c] += qv[a] * kv[c];
    }
    __syncthreads();
  }
#pragma unroll
  for (int a = 0; a < 3; ++a)
#pragma unroll
    for (int c = 0; c < 3; ++c)
      partials[(size_t)split * (HD * HD) + (i0 + a) * HD + (j0 + c)] = acc[a][c];
}

__global__ __launch_bounds__(256) void gram_reduce_kernel(
    const float* __restrict__ partials, float* __restrict__ logits_bh) {
  int ij = blockIdx.x * 256 + threadIdx.x;
  if (ij >= HD * HD) return;
  float s = 0.f;
  for (int sp = 0; sp < 128; ++sp) s += partials[(size_t)sp * (HD * HD) + ij];
  logits_bh[ij] = s;
}

// ---------------------------------------------------------------------------
// softmax rows with L2-normalization + temperature folded in. In-place.
// ---------------------------------------------------------------------------
__global__ __launch_bounds__(64) void softmax_kernel(
    float* __restrict__ logits, const float* __restrict__ norms,
    const float* __restrict__ temperature) {
  int hh = blockIdx.x, b = blockIdx.y;
  int i = threadIdx.x;
  if (i >= HD) return;
  const float eps = 1e-12f;
  float temp = temperature[hh];
  float nq = fmaxf(norms[b * C2 + HD * hh + i], eps);
  float* row = logits + (((size_t)b * HEADS + hh) * HD + i) * HD;
  float vals[48];
  float mx = -1e30f;
#pragma unroll
  for (int j = 0; j < HD; ++j) {
    float nk = fmaxf(norms[b * C2 + CDIM + HD * hh + j], eps);
    float v = row[j] / (nq * nk) * temp;
    vals[j] = v;
    mx = fmaxf(mx, v);
  }
  float sum = 0.f;
#pragma unroll
  for (int j = 0; j < HD; ++j) {
    vals[j] = expf(vals[j] - mx);
    sum += vals[j];
  }
  float inv = 1.f / sum;
#pragma unroll
  for (int j = 0; j < HD; ++j) row[j] = vals[j] * inv;
}

// ---------------------------------------------------------------------------
// M[b][oc][d] = sum_c proj[oc][48h(d)+c] * attn[b,h(d),c,d%48]  (proj folded)
// ---------------------------------------------------------------------------
__global__ __launch_bounds__(256) void buildM_kernel(
    const float* __restrict__ attn, const float* __restrict__ projw,
    float* __restrict__ M) {
  int idx = blockIdx.x * 256 + threadIdx.x;  // 2*192*192
  if (idx >= 2 * CDIM * CDIM) return;
  int d = idx % CDIM;
  int oc = (idx / CDIM) % CDIM;
  int b = idx / (CDIM * CDIM);
  int hh = d / HD, dd = d % HD;
  const float* arow = attn + ((size_t)b * HEADS + hh) * HD * HD;
  float s = 0.f;
#pragma unroll
  for (int c = 0; c < HD; ++c)
    s += projw[oc * CDIM + HD * hh + c] * arow[c * HD + dd];
  M[idx] = s;
}

// ---------------------------------------------------------------------------
// Fold M into the v 3x3 conv weights: Wp[b][oc][ic][tap] = sum_d M[b][oc][d]*Wv[d][ic][tap]
// ---------------------------------------------------------------------------
__global__ __launch_bounds__(256) void wtrans_kernel(
    const float* __restrict__ M, const float* __restrict__ Wv,
    float* __restrict__ Wp) {
  int oc = blockIdx.x;                 // 192
  int b = blockIdx.y;                  // 2
  const float* m = M + ((size_t)b * CDIM + oc) * CDIM;
  __shared__ float sM[CDIM];
  for (int i = threadIdx.x; i < CDIM; i += 256) sM[i] = m[i];
  __syncthreads();
  float* op = Wp + ((size_t)b * CDIM + oc) * (CDIM * 9);
  for (int e = threadIdx.x; e < CDIM * 9; e += 256) {
    float s = 0.f;
    for (int d = 0; d < CDIM; ++d) s += sM[d] * Wv[(size_t)d * (CDIM * 9) + e];
    op[e] = s;
  }
}

// ---------------------------------------------------------------------------
// full 3x3 conv (192->192), pad 1, per-batch call. Writes d_out directly.
// Tile: 64 oc x 64 px (one row segment).
// ---------------------------------------------------------------------------
__global__ __launch_bounds__(256) void conv3x3_kernel(
    const float* __restrict__ in, const float* __restrict__ wt,
    float* __restrict__ out) {
  const int oc0 = blockIdx.y * 64;
  const int pt = blockIdx.x;           // 1024 pixel tiles of 64
  const int h = pt >> 2;
  const int w0 = (pt & 3) * 64;

  __shared__ float sIn[16][3][68];     // 66 used (w0-1 .. w0+64)
  __shared__ float sW[16][9][64];      // [ic][tap][oc]

  const int t = threadIdx.x;
  const int tx = t & 15;               // pixel group (4 px)
  const int ty = t >> 4;               // oc group (4 oc)

  float acc[4][4];
#pragma unroll
  for (int i = 0; i < 4; ++i)
#pragma unroll
    for (int j = 0; j < 4; ++j) acc[i][j] = 0.f;

  for (int ic0 = 0; ic0 < CDIM; ic0 += 16) {
    for (int e = t; e < 16 * 3 * 66; e += 256) {
      int ic = e / 198;
      int r = (e % 198) / 66;
      int cc = e % 66;
      int hh = h - 1 + r;
      int ww = w0 - 1 + cc;
      float v = 0.f;
      if ((unsigned)hh < 256u && (unsigned)ww < 256u)
        v = in[(size_t)(ic0 + ic) * NPIX + hh * 256 + ww];
      sIn[ic][r][cc] = v;
    }
    for (int e = t; e < 16 * 9 * 64; e += 256) {
      int ic = e / 576;
      int rem = e % 576;
      int tap = rem >> 6;
      int oc = rem & 63;
      sW[ic][tap][oc] = wt[(size_t)(oc0 + oc) * (CDIM * 9) + (ic0 + ic) * 9 + tap];
    }
    __syncthreads();
#pragma unroll
    for (int ic = 0; ic < 16; ++ic) {
#pragma unroll
      for (int tap = 0; tap < 9; ++tap) {
        const int r = tap / 3, cc = tap % 3;
        float4 wv = *(float4*)&sW[ic][tap][ty * 4];
        float xv[4];
#pragma unroll
        for (int j = 0; j < 4; ++j) xv[j] = sIn[ic][r][cc + tx * 4 + j];
#pragma unroll
        for (int j = 0; j < 4; ++j) {
          acc[0][j] += wv.x * xv[j];
          acc[1][j] += wv.y * xv[j];
          acc[2][j] += wv.z * xv[j];
          acc[3][j] += wv.w * xv[j];
        }
      }
    }
    __syncthreads();
  }
#pragma unroll
  for (int i = 0; i < 4; ++i) {
    size_t row = (size_t)(oc0 + ty * 4 + i) * NPIX + h * 256 + w0 + tx * 4;
    *(float4*)&out[row] = make_float4(acc[i][0], acc[i][1], acc[i][2], acc[i][3]);
  }
}

// ---------------------------------------------------------------------------
extern "C" void kernel_launch(void* const* d_in, const int* in_sizes, int n_in,
                              void* d_out, int out_size, void* d_ws, size_t ws_size,
                              hipStream_t stream) {
  const float* x          = (const float*)d_in[0];
  const float* y          = (const float*)d_in[1];
  const float* qk_w       = (const float*)d_in[2];
  const float* qk_dw_w    = (const float*)d_in[3];
  const float* v_w        = (const float*)d_in[4];
  const float* v_dw_w     = (const float*)d_in[5];
  const float* proj_w     = (const float*)d_in[6];
  const float* temperature= (const float*)d_in[7];
  float* out = (float*)d_out;

  // Workspace layout (floats). Peak ~54.6 MB.
  float* A        = (float*)d_ws;                    // 96*NPIX   (25.2 MB)
  float* B        = A + (size_t)96 * NPIX;           // 96*NPIX   (25.2 MB)
  float* partials = B + (size_t)96 * NPIX;           // 128*2304  (1.18 MB)
  float* norms    = partials + 128 * HD * HD;        // 768
  float* logits   = norms + 768;                     // 2*4*48*48
  float* M        = logits + 2 * HEADS * HD * HD;    // 2*192*192
  float* Wp       = M + 2 * CDIM * CDIM;             // 2*192*192*9 (2.65 MB)
  size_t needF = (size_t)(Wp - (float*)d_ws) + (size_t)2 * CDIM * CDIM * 9;
  if (ws_size < needF * sizeof(float)) return;  // clean fail, not a GPU fault

  dim3 blk(256);

  // ---- qk path, per (batch, head): 96-ch chunk through A -> B ----
  for (int b = 0; b < 2; ++b) {
    const float* xb = x + (size_t)b * CDIM * NPIX;
    for (int h = 0; h < HEADS; ++h) {
      // q rows 48h..48h+47 -> A[0:48], k rows 192+48h.. -> A[48:96]
      gemm1x1_kernel<<<dim3(512, 1), blk, 0, stream>>>(
          xb, qk_w, A, CDIM, HD, HD * h);
      gemm1x1_kernel<<<dim3(512, 1), blk, 0, stream>>>(
          xb, qk_w, A + (size_t)HD * NPIX, CDIM, HD, CDIM + HD * h);
      dwconv96_kernel<<<dim3(96 * NPIX / 256), blk, 0, stream>>>(
          A, qk_dw_w, B, HD * h, CDIM + HD * h);
      norm96_kernel<<<dim3(96), blk, 0, stream>>>(
          B, norms, b * C2 + HD * h, b * C2 + CDIM + HD * h);
      gram_partial_kernel<<<dim3(128), blk, 0, stream>>>(B, partials);
      gram_reduce_kernel<<<dim3(9), blk, 0, stream>>>(
          partials, logits + ((size_t)b * HEADS + h) * HD * HD);
    }
  }
  // ---- attention matrix + proj fold + weight transform ----
  softmax_kernel<<<dim3(4, 2), dim3(64), 0, stream>>>(logits, norms, temperature);
  buildM_kernel<<<dim3(288), blk, 0, stream>>>(logits, proj_w, M);
  wtrans_kernel<<<dim3(CDIM, 2), blk, 0, stream>>>(M, v_dw_w, Wp);

  // ---- v path per batch: v1 = 1x1(y) into A..B (contiguous 192 ch), then
  //      out_b = conv3x3(v1, Wp_b) straight into d_out ----
  for (int b = 0; b < 2; ++b) {
    gemm1x1_kernel<<<dim3(512, 3), blk, 0, stream>>>(
        y + (size_t)b * CDIM * NPIX, v_w, A, CDIM, CDIM, 0);
    conv3x3_kernel<<<dim3(1024, 3), blk, 0, stream>>>(
        A, Wp + (size_t)b * CDIM * CDIM * 9, out + (size_t)b * CDIM * NPIX);
  }
}

// Round 3
// 1515.716 us; speedup vs baseline: 2.3156x; 2.3156x over previous
//
#include <hip/hip_runtime.h>
#include <hip/hip_bf16.h>

#define NPIX 65536
#define CDIM 192
#define C2   384
#define HEADS 4
#define HD   48
#define PROW 258                    // padded row length (256 + 2)
#define XTROWS (PROW * PROW)        // 66564 padded pixel rows

typedef float f32x4 __attribute__((ext_vector_type(4)));
typedef short short8 __attribute__((ext_vector_type(8)));

__device__ __forceinline__ unsigned short f2bf(float x) {
  union { float f; unsigned u; } v; v.f = x;
  unsigned r = v.u + 0x7fff + ((v.u >> 16) & 1);   // RNE
  return (unsigned short)(r >> 16);
}

__device__ __forceinline__ void gload_lds16(const void* g, void* l) {
  __builtin_amdgcn_global_load_lds(
      (const __attribute__((address_space(1))) unsigned int*)g,
      (__attribute__((address_space(3))) unsigned int*)l, 16, 0, 0);
}

// ---------------------------------------------------------------------------
// 1x1 conv as GEMM (f32 out): Out[oc][n] = sum_c W[wRowOff+oc][c] * X[c][n].
// Used for the qk path (48-oc chunks, masked rows).
// ---------------------------------------------------------------------------
__global__ __launch_bounds__(256) void gemm1x1_kernel(
    const float* __restrict__ X, const float* __restrict__ Wt,
    float* __restrict__ Out, int Cin, int ocValid, int wRowOff) {
  const int n0 = blockIdx.x * 128;
  const int m0 = blockIdx.y * 64;

  __shared__ float sX[32][128];
  __shared__ float sW[32][68];

  const int t = threadIdx.x;
  const int tx = t & 15;
  const int ty = t >> 4;

  float acc[4][8];
#pragma unroll
  for (int i = 0; i < 4; ++i)
#pragma unroll
    for (int j = 0; j < 8; ++j) acc[i][j] = 0.f;

  for (int k0 = 0; k0 < Cin; k0 += 32) {
#pragma unroll
    for (int it = 0; it < 4; ++it) {
      int e = t * 4 + it * 1024;
      int kk = e >> 7, col = e & 127;
      *(float4*)&sX[kk][col] =
          *(const float4*)&X[(size_t)(k0 + kk) * NPIX + n0 + col];
    }
#pragma unroll
    for (int it = 0; it < 2; ++it) {
      int e = t * 4 + it * 1024;
      int m = e >> 5, kk = e & 31;
      float4 wv = make_float4(0.f, 0.f, 0.f, 0.f);
      if (m0 + m < ocValid)
        wv = *(const float4*)&Wt[(size_t)(wRowOff + m0 + m) * Cin + k0 + kk];
      sW[kk + 0][m] = wv.x;
      sW[kk + 1][m] = wv.y;
      sW[kk + 2][m] = wv.z;
      sW[kk + 3][m] = wv.w;
    }
    __syncthreads();
#pragma unroll
    for (int kk = 0; kk < 32; ++kk) {
      float xv[8], wv[4];
      *(float4*)&xv[0] = *(float4*)&sX[kk][tx * 8];
      *(float4*)&xv[4] = *(float4*)&sX[kk][tx * 8 + 4];
      *(float4*)&wv[0] = *(float4*)&sW[kk][ty * 4];
#pragma unroll
      for (int i = 0; i < 4; ++i)
#pragma unroll
        for (int j = 0; j < 8; ++j) acc[i][j] += wv[i] * xv[j];
    }
    __syncthreads();
  }
#pragma unroll
  for (int i = 0; i < 4; ++i) {
    if (m0 + ty * 4 + i < ocValid) {
      size_t row = (size_t)(m0 + ty * 4 + i) * NPIX + n0 + tx * 8;
      *(float4*)&Out[row]     = make_float4(acc[i][0], acc[i][1], acc[i][2], acc[i][3]);
      *(float4*)&Out[row + 4] = make_float4(acc[i][4], acc[i][5], acc[i][6], acc[i][7]);
    }
  }
}

// ---------------------------------------------------------------------------
// v-path 1x1 GEMM with fused transposed/padded bf16 epilogue:
// writes Xt[(h+1)*258 + (w+1)][oc] (bf16) instead of v1[oc][px].
// Full 192 oc (no masking). Borders of Xt must be pre-zeroed (memset).
// ---------------------------------------------------------------------------
__global__ __launch_bounds__(256) void gemm1x1_tbf_kernel(
    const float* __restrict__ X, const float* __restrict__ Wt,
    unsigned short* __restrict__ Xt) {
  const int n0 = blockIdx.x * 128;
  const int m0 = blockIdx.y * 64;

  __shared__ float sX[32][128];     // 16 KB, aliased as bf16 out stage
  __shared__ float sW[32][68];

  const int t = threadIdx.x;
  const int tx = t & 15;
  const int ty = t >> 4;

  float acc[4][8];
#pragma unroll
  for (int i = 0; i < 4; ++i)
#pragma unroll
    for (int j = 0; j < 8; ++j) acc[i][j] = 0.f;

  for (int k0 = 0; k0 < CDIM; k0 += 32) {
#pragma unroll
    for (int it = 0; it < 4; ++it) {
      int e = t * 4 + it * 1024;
      int kk = e >> 7, col = e & 127;
      *(float4*)&sX[kk][col] =
          *(const float4*)&X[(size_t)(k0 + kk) * NPIX + n0 + col];
    }
#pragma unroll
    for (int it = 0; it < 2; ++it) {
      int e = t * 4 + it * 1024;
      int m = e >> 5, kk = e & 31;
      float4 wv = *(const float4*)&Wt[(size_t)(m0 + m) * CDIM + k0 + kk];
      sW[kk + 0][m] = wv.x;
      sW[kk + 1][m] = wv.y;
      sW[kk + 2][m] = wv.z;
      sW[kk + 3][m] = wv.w;
    }
    __syncthreads();
#pragma unroll
    for (int kk = 0; kk < 32; ++kk) {
      float xv[8], wv[4];
      *(float4*)&xv[0] = *(float4*)&sX[kk][tx * 8];
      *(float4*)&xv[4] = *(float4*)&sX[kk][tx * 8 + 4];
      *(float4*)&wv[0] = *(float4*)&sW[kk][ty * 4];
#pragma unroll
      for (int i = 0; i < 4; ++i)
#pragma unroll
        for (int j = 0; j < 8; ++j) acc[i][j] += wv[i] * xv[j];
    }
    __syncthreads();
  }
  // stage transposed bf16 tile [128 px][64 oc] into LDS (alias sX)
  short* sOut = (short*)sX;
#pragma unroll
  for (int i = 0; i < 4; ++i)
#pragma unroll
    for (int j = 0; j < 8; ++j)
      sOut[(tx * 8 + j) * 64 + ty * 4 + i] = (short)f2bf(acc[i][j]);
  __syncthreads();
  // write rows: px -> padded row, 64 oc (32 dwords) each
  for (int e = t; e < 128 * 32; e += 256) {
    int px = e >> 5, dg = e & 31;
    int pxg = n0 + px;
    int hh = pxg >> 8, ww = pxg & 255;
    size_t row = (size_t)(hh + 1) * PROW + (ww + 1);
    unsigned v = *(unsigned*)&sOut[px * 64 + dg * 2];
    *(unsigned*)&Xt[row * CDIM + m0 + dg * 2] = v;
  }
}

// ---------------------------------------------------------------------------
// MFMA conv3x3: out[oc][px] = sum_{tap,ic} Wb[tap][oc][ic] * Xt[pxrow+shift][ic]
// Block: 64 oc x 128 px. 4 waves: wm=wid&1 (32 oc), wn=wid>>1 (64 px).
// K loop: 9 taps x 6 chunks of 32 ic. LDS staged via global_load_lds (16B).
// ---------------------------------------------------------------------------
__global__ __launch_bounds__(256) void conv3x3_mfma_kernel(
    const unsigned short* __restrict__ Xt,   // [XTROWS][192] bf16 padded
    const unsigned short* __restrict__ Wb,   // [9][192][192] bf16
    float* __restrict__ out) {
  const int pt = blockIdx.x;             // 512 pixel tiles of 128
  const int h = pt >> 1;
  const int w0 = (pt & 1) * 128;
  const int oc0 = blockIdx.y * 64;

  __shared__ short sA[64 * 32];          // [oc][ic]  4 KB
  __shared__ short sB[128 * 32];         // [px][ic]  8 KB

  const int t = threadIdx.x;
  const int lane = t & 63;
  const int wid = t >> 6;
  const int wm = wid & 1;                // oc half
  const int wn = wid >> 1;               // px half

  f32x4 zero = {0.f, 0.f, 0.f, 0.f};
  f32x4 acc[2][4];
#pragma unroll
  for (int mi = 0; mi < 2; ++mi)
#pragma unroll
    for (int ni = 0; ni < 4; ++ni) acc[mi][ni] = zero;

  const int lrow = lane >> 2;            // 0..15
  const int lcg  = (lane & 3) * 8;       // ic sub-offset (8 bf16 = 16 B)

  for (int tap = 0; tap < 9; ++tap) {
    const int r = tap / 3, c = tap % 3;
    const unsigned short* bsrc =
        Xt + ((size_t)(h + r) * PROW + w0 + c) * CDIM;
    const unsigned short* asrc =
        Wb + ((size_t)tap * CDIM + oc0) * CDIM;
    for (int ic0 = 0; ic0 < CDIM; ic0 += 32) {
      // stage A: wave wid stages oc rows [wid*16, wid*16+16)
      gload_lds16(asrc + (size_t)(wid * 16 + lrow) * CDIM + ic0 + lcg,
                  sA + wid * 16 * 32);
      // stage B: 128 px rows, wave wid stages rows wid*16 + {0,64}
#pragma unroll
      for (int it = 0; it < 2; ++it) {
        int rb = it * 64 + wid * 16;
        gload_lds16(bsrc + (size_t)(rb + lrow) * CDIM + ic0 + lcg,
                    sB + rb * 32);
      }
      asm volatile("s_waitcnt vmcnt(0)");
      __syncthreads();
      short8 af[2], bf[4];
#pragma unroll
      for (int mi = 0; mi < 2; ++mi)
        af[mi] = *(const short8*)&sA[(wm * 32 + mi * 16 + (lane & 15)) * 32 +
                                     (lane >> 4) * 8];
#pragma unroll
      for (int ni = 0; ni < 4; ++ni)
        bf[ni] = *(const short8*)&sB[(wn * 64 + ni * 16 + (lane & 15)) * 32 +
                                     (lane >> 4) * 8];
#pragma unroll
      for (int mi = 0; mi < 2; ++mi)
#pragma unroll
        for (int ni = 0; ni < 4; ++ni)
          acc[mi][ni] = __builtin_amdgcn_mfma_f32_16x16x32_bf16(
              af[mi], bf[ni], acc[mi][ni], 0, 0, 0);
      __syncthreads();
    }
  }
  // C/D layout: col = lane&15 (px), row = (lane>>4)*4 + reg (oc)
#pragma unroll
  for (int mi = 0; mi < 2; ++mi) {
    int ocl = oc0 + wm * 32 + mi * 16 + (lane >> 4) * 4;
#pragma unroll
    for (int ni = 0; ni < 4; ++ni) {
      int wloc = w0 + wn * 64 + ni * 16 + (lane & 15);
#pragma unroll
      for (int rg = 0; rg < 4; ++rg)
        out[(size_t)(ocl + rg) * NPIX + h * 256 + wloc] = acc[mi][ni][rg];
    }
  }
}

// ---------------------------------------------------------------------------
// depthwise 3x3, pad 1, on a 96-channel chunk (48 q + 48 k of one head).
// ---------------------------------------------------------------------------
__global__ __launch_bounds__(256) void dwconv96_kernel(
    const float* __restrict__ in, const float* __restrict__ dw,
    float* __restrict__ out, int qoff, int koff) {
  int idx = blockIdx.x * 256 + threadIdx.x;
  int wcol = idx & 255;
  int hrow = (idx >> 8) & 255;
  int c = idx >> 16;
  int wrow = (c < HD) ? (qoff + c) : (koff + c - HD);
  const float* ip = in + (size_t)c * NPIX;
  const float* wp = dw + wrow * 9;
  float s = 0.f;
#pragma unroll
  for (int r = -1; r <= 1; ++r) {
    int hh = hrow + r;
    if ((unsigned)hh < 256u) {
#pragma unroll
      for (int cc = -1; cc <= 1; ++cc) {
        int ww = wcol + cc;
        if ((unsigned)ww < 256u)
          s += wp[(r + 1) * 3 + (cc + 1)] * ip[hh * 256 + ww];
      }
    }
  }
  out[idx] = s;
}

// ---------------------------------------------------------------------------
__global__ __launch_bounds__(256) void norm96_kernel(
    const float* __restrict__ qkdw, float* __restrict__ norms,
    int nqoff, int nkoff) {
  int ch = blockIdx.x;
  const float* p = qkdw + (size_t)ch * NPIX;
  int t = threadIdx.x;
  float s = 0.f;
  for (int i = t * 4; i < NPIX; i += 1024) {
    float4 v = *(const float4*)&p[i];
    s += v.x * v.x + v.y * v.y + v.z * v.z + v.w * v.w;
  }
#pragma unroll
  for (int off = 32; off > 0; off >>= 1) s += __shfl_down(s, off);
  __shared__ float red[4];
  if ((t & 63) == 0) red[t >> 6] = s;
  __syncthreads();
  if (t == 0) {
    int g = (ch < HD) ? (nqoff + ch) : (nkoff + ch - HD);
    norms[g] = sqrtf(red[0] + red[1] + red[2] + red[3]);
  }
}

// ---------------------------------------------------------------------------
__global__ __launch_bounds__(256) void gram_partial_kernel(
    const float* __restrict__ qkdw, float* __restrict__ partials) {
  const int split = blockIdx.x;
  const float* qp = qkdw;
  const float* kp = qkdw + (size_t)HD * NPIX;

  __shared__ float sQ[48][132];
  __shared__ float sK[48][132];

  const int t = threadIdx.x;
  const int i0 = (t & 15) * 3;
  const int j0 = (t >> 4) * 3;
  float acc[3][3];
#pragma unroll
  for (int a = 0; a < 3; ++a)
#pragma unroll
    for (int c = 0; c < 3; ++c) acc[a][c] = 0.f;

  for (int sub = 0; sub < 4; ++sub) {
    int nb = split * 512 + sub * 128;
    for (int e = t * 4; e < 48 * 128; e += 1024) {
      int row = e >> 7, col = e & 127;
      *(float4*)&sQ[row][col] = *(const float4*)&qp[(size_t)row * NPIX + nb + col];
      *(float4*)&sK[row][col] = *(const float4*)&kp[(size_t)row * NPIX + nb + col];
    }
    __syncthreads();
#pragma unroll 8
    for (int nn = 0; nn < 128; ++nn) {
      float qv[3], kv[3];
#pragma unroll
      for (int a = 0; a < 3; ++a) qv[a] = sQ[i0 + a][nn];
#pragma unroll
      for (int c = 0; c < 3; ++c) kv[c] = sK[j0 + c][nn];
#pragma unroll
      for (int a = 0; a < 3; ++a)
#pragma unroll
        for (int c = 0; c < 3; ++c) acc[a][c] += qv[a] * kv[c];
    }
    __syncthreads();
  }
#pragma unroll
  for (int a = 0; a < 3; ++a)
#pragma unroll
    for (int c = 0; c < 3; ++c)
      partials[(size_t)split * (HD * HD) + (i0 + a) * HD + (j0 + c)] = acc[a][c];
}

__global__ __launch_bounds__(256) void gram_reduce_kernel(
    const float* __restrict__ partials, float* __restrict__ logits_bh) {
  int ij = blockIdx.x * 256 + threadIdx.x;
  if (ij >= HD * HD) return;
  float s = 0.f;
  for (int sp = 0; sp < 128; ++sp) s += partials[(size_t)sp * (HD * HD) + ij];
  logits_bh[ij] = s;
}

// ---------------------------------------------------------------------------
__global__ __launch_bounds__(64) void softmax_kernel(
    float* __restrict__ logits, const float* __restrict__ norms,
    const float* __restrict__ temperature) {
  int hh = blockIdx.x, b = blockIdx.y;
  int i = threadIdx.x;
  if (i >= HD) return;
  const float eps = 1e-12f;
  float temp = temperature[hh];
  float nq = fmaxf(norms[b * C2 + HD * hh + i], eps);
  float* row = logits + (((size_t)b * HEADS + hh) * HD + i) * HD;
  float vals[48];
  float mx = -1e30f;
#pragma unroll
  for (int j = 0; j < HD; ++j) {
    float nk = fmaxf(norms[b * C2 + CDIM + HD * hh + j], eps);
    float v = row[j] / (nq * nk) * temp;
    vals[j] = v;
    mx = fmaxf(mx, v);
  }
  float sum = 0.f;
#pragma unroll
  for (int j = 0; j < HD; ++j) {
    vals[j] = expf(vals[j] - mx);
    sum += vals[j];
  }
  float inv = 1.f / sum;
#pragma unroll
  for (int j = 0; j < HD; ++j) row[j] = vals[j] * inv;
}

// ---------------------------------------------------------------------------
__global__ __launch_bounds__(256) void buildM_kernel(
    const float* __restrict__ attn, const float* __restrict__ projw,
    float* __restrict__ M) {
  int idx = blockIdx.x * 256 + threadIdx.x;
  if (idx >= 2 * CDIM * CDIM) return;
  int d = idx % CDIM;
  int oc = (idx / CDIM) % CDIM;
  int b = idx / (CDIM * CDIM);
  int hh = d / HD, dd = d % HD;
  const float* arow = attn + ((size_t)b * HEADS + hh) * HD * HD;
  float s = 0.f;
#pragma unroll
  for (int c = 0; c < HD; ++c)
    s += projw[oc * CDIM + HD * hh + c] * arow[c * HD + dd];
  M[idx] = s;
}

// ---------------------------------------------------------------------------
// Wb[b][tap][oc][ic] (bf16) = sum_d M[b][oc][d] * Wv[d][ic][tap]
// ---------------------------------------------------------------------------
__global__ __launch_bounds__(256) void wtrans_kernel(
    const float* __restrict__ M, const float* __restrict__ Wv,
    unsigned short* __restrict__ Wb) {
  int oc = blockIdx.x;
  int b = blockIdx.y;
  const float* m = M + ((size_t)b * CDIM + oc) * CDIM;
  __shared__ float sM[CDIM];
  for (int i = threadIdx.x; i < CDIM; i += 256) sM[i] = m[i];
  __syncthreads();
  for (int e = threadIdx.x; e < CDIM * 9; e += 256) {
    int ic = e / 9, tap = e % 9;
    float s = 0.f;
    for (int d = 0; d < CDIM; ++d) s += sM[d] * Wv[(size_t)d * (CDIM * 9) + e];
    Wb[(((size_t)b * 9 + tap) * CDIM + oc) * CDIM + ic] = f2bf(s);
  }
}

// ---------------------------------------------------------------------------
extern "C" void kernel_launch(void* const* d_in, const int* in_sizes, int n_in,
                              void* d_out, int out_size, void* d_ws, size_t ws_size,
                              hipStream_t stream) {
  const float* x          = (const float*)d_in[0];
  const float* y          = (const float*)d_in[1];
  const float* qk_w       = (const float*)d_in[2];
  const float* qk_dw_w    = (const float*)d_in[3];
  const float* v_w        = (const float*)d_in[4];
  const float* v_dw_w     = (const float*)d_in[5];
  const float* proj_w     = (const float*)d_in[6];
  const float* temperature= (const float*)d_in[7];
  float* out = (float*)d_out;

  // Workspace layout. Peak ~79 MB.
  float* A        = (float*)d_ws;                    // 96*NPIX f32 (25.2 MB)
  float* B        = A + (size_t)96 * NPIX;           // 96*NPIX f32 (25.2 MB)
  float* partials = B + (size_t)96 * NPIX;           // 128*2304
  float* norms    = partials + 128 * HD * HD;        // 768
  float* logits   = norms + 768;                     // 4608
  float* M        = logits + 2 * HEADS * HD * HD;    // 73728
  unsigned short* Wb = (unsigned short*)(M + 2 * CDIM * CDIM);  // 2*9*192*192 bf16
  unsigned short* Xt = Wb + (size_t)2 * 9 * CDIM * CDIM;        // XTROWS*192 bf16
  size_t needB = (size_t)((char*)(Xt + (size_t)XTROWS * CDIM) - (char*)d_ws);
  if (ws_size < needB) return;  // clean fail instead of GPU fault

  dim3 blk(256);

  // ---- qk path, per (batch, head): 96-ch chunk through A -> B ----
  for (int b = 0; b < 2; ++b) {
    const float* xb = x + (size_t)b * CDIM * NPIX;
    for (int h = 0; h < HEADS; ++h) {
      gemm1x1_kernel<<<dim3(512, 1), blk, 0, stream>>>(
          xb, qk_w, A, CDIM, HD, HD * h);
      gemm1x1_kernel<<<dim3(512, 1), blk, 0, stream>>>(
          xb, qk_w, A + (size_t)HD * NPIX, CDIM, HD, CDIM + HD * h);
      dwconv96_kernel<<<dim3(96 * NPIX / 256), blk, 0, stream>>>(
          A, qk_dw_w, B, HD * h, CDIM + HD * h);
      norm96_kernel<<<dim3(96), blk, 0, stream>>>(
          B, norms, b * C2 + HD * h, b * C2 + CDIM + HD * h);
      gram_partial_kernel<<<dim3(128), blk, 0, stream>>>(B, partials);
      gram_reduce_kernel<<<dim3(9), blk, 0, stream>>>(
          partials, logits + ((size_t)b * HEADS + h) * HD * HD);
    }
  }
  // ---- attention matrix + proj fold + weight transform (bf16) ----
  softmax_kernel<<<dim3(4, 2), dim3(64), 0, stream>>>(logits, norms, temperature);
  buildM_kernel<<<dim3(288), blk, 0, stream>>>(logits, proj_w, M);
  wtrans_kernel<<<dim3(CDIM, 2), blk, 0, stream>>>(M, v_dw_w, Wb);

  // ---- v path per batch: 1x1(y) fused with bf16 transpose/pad -> Xt,
  //      then MFMA conv3x3 with folded weights straight into d_out ----
  for (int b = 0; b < 2; ++b) {
    hipMemsetAsync(Xt, 0, (size_t)XTROWS * CDIM * sizeof(unsigned short), stream);
    gemm1x1_tbf_kernel<<<dim3(512, 3), blk, 0, stream>>>(
        y + (size_t)b * CDIM * NPIX, v_w, Xt);
    conv3x3_mfma_kernel<<<dim3(512, 3), blk, 0, stream>>>(
        Xt, Wb + (size_t)b * 9 * CDIM * CDIM, out + (size_t)b * CDIM * NPIX);
  }
}

// Round 4
// 573.917 us; speedup vs baseline: 6.1156x; 2.6410x over previous
//
#include <hip/hip_runtime.h>
#include <hip/hip_bf16.h>

#define NPIX 65536
#define CDIM 192
#define C2   384
#define HEADS 4
#define HD   48
#define PROW 258                    // padded row length (256 + 2)
#define XTROWS (PROW * PROW)        // 66564 padded pixel rows

typedef float f32x4 __attribute__((ext_vector_type(4)));
typedef short short8 __attribute__((ext_vector_type(8)));

__device__ __forceinline__ unsigned short f2bf(float x) {
  union { float f; unsigned u; } v; v.f = x;
  unsigned r = v.u + 0x7fff + ((v.u >> 16) & 1);   // RNE
  return (unsigned short)(r >> 16);
}
__device__ __forceinline__ float bf2f(unsigned short x) {
  union { unsigned u; float f; } v; v.u = ((unsigned)x) << 16;
  return v.f;
}

__device__ __forceinline__ void gload_lds16(const void* g, void* l) {
  __builtin_amdgcn_global_load_lds(
      (const __attribute__((address_space(1))) unsigned int*)g,
      (__attribute__((address_space(3))) unsigned int*)l, 16, 0, 0);
}

// ---------------------------------------------------------------------------
// cast weights to bf16 once
// ---------------------------------------------------------------------------
__global__ __launch_bounds__(256) void castw_kernel(
    const float* __restrict__ qkw, const float* __restrict__ vw,
    unsigned short* __restrict__ wqk, unsigned short* __restrict__ wv) {
  int i = blockIdx.x * 256 + threadIdx.x;
  if (i < C2 * CDIM) wqk[i] = f2bf(qkw[i]);
  if (i < CDIM * CDIM) wv[i] = f2bf(vw[i]);
}

// ---------------------------------------------------------------------------
// qk 1x1 conv as MFMA GEMM: Out[oc][px] (bf16) = W[384][192] @ X[192][px].
// Block: 512 thr (8 waves), tile M=384 (full, x read once), N=64 px, K=192.
// B staged with fused f32->bf16 transpose (LDS [px][40] pad, 16B-aligned rows).
// A staged linear [oc][32] via global_load_lds.
// ---------------------------------------------------------------------------
__global__ __launch_bounds__(512) void qk_mfma_kernel(
    const float* __restrict__ X, const unsigned short* __restrict__ W,
    unsigned short* __restrict__ Out) {
  const int px0 = blockIdx.x * 64;
  __shared__ short sA[C2 * 32];    // 24576 B
  __shared__ short sB[64 * 40];    // 5120 B
  const int t = threadIdx.x;
  const int lane = t & 63;
  const int wid = t >> 6;          // 0..7 -> oc rows wid*48..+47
  const int cp = t & 15;           // channel pair
  const int pg = t >> 4;           // 0..31 -> px = 2pg

  f32x4 acc[3][4];
#pragma unroll
  for (int mi = 0; mi < 3; ++mi)
#pragma unroll
    for (int ni = 0; ni < 4; ++ni) acc[mi][ni] = (f32x4){0.f, 0.f, 0.f, 0.f};

  for (int k0 = 0; k0 < CDIM; k0 += 32) {
    // A stage: 1536 16B chunks, 3 issues x 512 lanes
#pragma unroll
    for (int i = 0; i < 3; ++i) {
      int e = i * 512 + t;
      int oc = e >> 2, kg = e & 3;
      gload_lds16(W + (size_t)oc * CDIM + k0 + kg * 8,
                  (char*)sA + ((size_t)i * 512 + (t & ~63)) * 16);
    }
    // B stage: fused transpose-cast, packed ch-pair dwords
    {
      const float* xp = X + (size_t)(k0 + 2 * cp) * NPIX + px0 + 2 * pg;
      float2 a = *(const float2*)xp;
      float2 b = *(const float2*)(xp + NPIX);
      unsigned d0 = (unsigned)f2bf(a.x) | ((unsigned)f2bf(b.x) << 16);
      unsigned d1 = (unsigned)f2bf(a.y) | ((unsigned)f2bf(b.y) << 16);
      *(unsigned*)&sB[(2 * pg) * 40 + 2 * cp] = d0;
      *(unsigned*)&sB[(2 * pg + 1) * 40 + 2 * cp] = d1;
    }
    asm volatile("s_waitcnt vmcnt(0)");
    __syncthreads();
    short8 af[3], bf[4];
#pragma unroll
    for (int mi = 0; mi < 3; ++mi)
      af[mi] = *(const short8*)&sA[(wid * 48 + mi * 16 + (lane & 15)) * 32 +
                                   (lane >> 4) * 8];
#pragma unroll
    for (int ni = 0; ni < 4; ++ni)
      bf[ni] = *(const short8*)&sB[(ni * 16 + (lane & 15)) * 40 +
                                   (lane >> 4) * 8];
#pragma unroll
    for (int mi = 0; mi < 3; ++mi)
#pragma unroll
      for (int ni = 0; ni < 4; ++ni)
        acc[mi][ni] = __builtin_amdgcn_mfma_f32_16x16x32_bf16(
            af[mi], bf[ni], acc[mi][ni], 0, 0, 0);
    __syncthreads();
  }
  // D: col=lane&15 (px), row=(lane>>4)*4+reg (oc)
#pragma unroll
  for (int mi = 0; mi < 3; ++mi) {
    int ocb = wid * 48 + mi * 16 + (lane >> 4) * 4;
#pragma unroll
    for (int ni = 0; ni < 4; ++ni) {
      int px = px0 + ni * 16 + (lane & 15);
#pragma unroll
      for (int rg = 0; rg < 4; ++rg)
        Out[(size_t)(ocb + rg) * NPIX + px] = f2bf(acc[mi][ni][rg]);
    }
  }
}

// ---------------------------------------------------------------------------
// v 1x1 conv as MFMA, output transposed straight into padded Xt (bf16):
// Xt[(h+1)*258 + w+1][oc] = sum_c v_w[oc][c] * Y[c][px].
// A = Y-pixels (m=px), B = weights (n=oc): D row=px, col=oc.
// Block: 256 thr (4 waves), tile M=64 px, N=192 oc (full), K=192.
// ---------------------------------------------------------------------------
__global__ __launch_bounds__(256) void v_mfma_kernel(
    const float* __restrict__ Y, const unsigned short* __restrict__ W,
    unsigned short* __restrict__ Xt) {
  const int px0 = blockIdx.x * 64;
  const int h = px0 >> 8;
  const int w0 = px0 & 255;
  __shared__ short sX[64 * 40];    // [px][40ch pad] 5120 B
  __shared__ short sW[CDIM * 32];  // [oc][32] 12288 B
  const int t = threadIdx.x;
  const int lane = t & 63;
  const int wid = t >> 6;          // 0..3 -> px rows wid*16..+15
  const int cp = t & 15;
  const int pg = t >> 4;           // 0..15 -> px = 4pg..+3

  f32x4 acc[12];
#pragma unroll
  for (int ni = 0; ni < 12; ++ni) acc[ni] = (f32x4){0.f, 0.f, 0.f, 0.f};

  for (int k0 = 0; k0 < CDIM; k0 += 32) {
    // W stage: 768 chunks, 3 issues x 256 lanes
#pragma unroll
    for (int i = 0; i < 3; ++i) {
      int e = i * 256 + t;
      int oc = e >> 2, kg = e & 3;
      gload_lds16(W + (size_t)oc * CDIM + k0 + kg * 8,
                  (char*)sW + ((size_t)i * 256 + (t & ~63)) * 16);
    }
    // X stage: fused transpose-cast
    {
      const float* xp = Y + (size_t)(k0 + 2 * cp) * NPIX + px0 + 4 * pg;
      float4 a = *(const float4*)xp;
      float4 b = *(const float4*)(xp + NPIX);
      float av[4] = {a.x, a.y, a.z, a.w};
      float bv[4] = {b.x, b.y, b.z, b.w};
#pragma unroll
      for (int i = 0; i < 4; ++i) {
        unsigned d = (unsigned)f2bf(av[i]) | ((unsigned)f2bf(bv[i]) << 16);
        *(unsigned*)&sX[(4 * pg + i) * 40 + 2 * cp] = d;
      }
    }
    asm volatile("s_waitcnt vmcnt(0)");
    __syncthreads();
    short8 af = *(const short8*)&sX[(wid * 16 + (lane & 15)) * 40 +
                                    (lane >> 4) * 8];
    short8 bf[12];
#pragma unroll
    for (int ni = 0; ni < 12; ++ni)
      bf[ni] = *(const short8*)&sW[(ni * 16 + (lane & 15)) * 32 +
                                   (lane >> 4) * 8];
#pragma unroll
    for (int ni = 0; ni < 12; ++ni)
      acc[ni] = __builtin_amdgcn_mfma_f32_16x16x32_bf16(af, bf[ni], acc[ni],
                                                        0, 0, 0);
    __syncthreads();
  }
  // D: row = px (m), col = oc (n). Write into padded Xt rows.
  const int pxl = wid * 16 + (lane >> 4) * 4;
#pragma unroll
  for (int ni = 0; ni < 12; ++ni) {
    int oc = ni * 16 + (lane & 15);
#pragma unroll
    for (int rg = 0; rg < 4; ++rg) {
      size_t xrow = (size_t)(h + 1) * PROW + (w0 + pxl + rg + 1);
      Xt[xrow * CDIM + oc] = f2bf(acc[ni][rg]);
    }
  }
}

// ---------------------------------------------------------------------------
// depthwise 3x3 (bf16 in/out) on one head's 96-ch chunk + fused sumsq partial.
// qkb rows: q = qrow0+c (c<48), k = krow0+c-48. Same indices for dw weights.
// ---------------------------------------------------------------------------
__global__ __launch_bounds__(256) void dwconv96_kernel(
    const unsigned short* __restrict__ qkb, const float* __restrict__ dw,
    unsigned short* __restrict__ out, float* __restrict__ ssp,
    int qrow0, int krow0) {
  const int t = threadIdx.x;
  const int ch = blockIdx.y;            // 0..95
  const int chunk = blockIdx.x;         // 0..31
  const int px0 = chunk * 2048 + t * 8;
  const int hh = px0 >> 8;
  const int w0 = px0 & 255;
  const int srcrow = (ch < HD) ? (qrow0 + ch) : (krow0 + ch - HD);
  const unsigned short* ip = qkb + (size_t)srcrow * NPIX;

  float win[3][10];
#pragma unroll
  for (int r = 0; r < 3; ++r) {
    int hr = hh - 1 + r;
    if ((unsigned)hr < 256u) {
      const unsigned short* rp = ip + hr * 256 + w0;
      short8 v = *(const short8*)rp;
#pragma unroll
      for (int j = 0; j < 8; ++j) win[r][j + 1] = bf2f((unsigned short)v[j]);
      win[r][0] = w0 ? bf2f(rp[-1]) : 0.f;
      win[r][9] = (w0 < 248) ? bf2f(rp[8]) : 0.f;
    } else {
#pragma unroll
      for (int j = 0; j < 10; ++j) win[r][j] = 0.f;
    }
  }
  const float* wp = dw + (size_t)srcrow * 9;
  float wr[9];
#pragma unroll
  for (int i = 0; i < 9; ++i) wr[i] = wp[i];

  short8 ov;
  float ss = 0.f;
#pragma unroll
  for (int j = 0; j < 8; ++j) {
    float s = 0.f;
#pragma unroll
    for (int r = 0; r < 3; ++r)
#pragma unroll
      for (int c = 0; c < 3; ++c) s += wr[r * 3 + c] * win[r][j + c];
    ss += s * s;
    ov[j] = (short)f2bf(s);
  }
  *(short8*)&out[(size_t)ch * NPIX + px0] = ov;

#pragma unroll
  for (int off = 32; off; off >>= 1) ss += __shfl_down(ss, off);
  __shared__ float red[4];
  if ((t & 63) == 0) red[t >> 6] = ss;
  __syncthreads();
  if (t == 0) ssp[ch * 32 + chunk] = red[0] + red[1] + red[2] + red[3];
}

// ---------------------------------------------------------------------------
// Gram via MFMA: part[wave][qi][kj] = sum over wave's 512-px K-range.
// qkd: [96][65536] bf16 (rows 0-47 q, 48-95 k). Grid: 32 blocks x 4 waves.
// ---------------------------------------------------------------------------
__global__ __launch_bounds__(256) void gram_kernel(
    const unsigned short* __restrict__ qkd, float* __restrict__ part) {
  const int t = threadIdx.x;
  const int lane = t & 63;
  const int wid = t >> 6;
  __shared__ short sG[4][96 * 32];      // 24576 B total
  short* zone = sG[wid];
  const int kbase = (blockIdx.x * 4 + wid) * 512;

  f32x4 acc[3][3];
#pragma unroll
  for (int mi = 0; mi < 3; ++mi)
#pragma unroll
    for (int nj = 0; nj < 3; ++nj) acc[mi][nj] = (f32x4){0.f, 0.f, 0.f, 0.f};

  for (int s = 0; s < 16; ++s) {
    const int kpos = kbase + s * 32;
#pragma unroll
    for (int i = 0; i < 6; ++i) {
      int e = i * 64 + lane;
      int ch = e >> 2, pxg = e & 3;
      gload_lds16(qkd + (size_t)ch * NPIX + kpos + pxg * 8,
                  (char*)zone + (size_t)i * 1024);
    }
    asm volatile("s_waitcnt vmcnt(0)");
    __syncthreads();
    short8 qf[3], kf[3];
#pragma unroll
    for (int mi = 0; mi < 3; ++mi)
      qf[mi] = *(const short8*)&zone[(mi * 16 + (lane & 15)) * 32 +
                                     (lane >> 4) * 8];
#pragma unroll
    for (int nj = 0; nj < 3; ++nj)
      kf[nj] = *(const short8*)&zone[(HD + nj * 16 + (lane & 15)) * 32 +
                                     (lane >> 4) * 8];
#pragma unroll
    for (int mi = 0; mi < 3; ++mi)
#pragma unroll
      for (int nj = 0; nj < 3; ++nj)
        acc[mi][nj] = __builtin_amdgcn_mfma_f32_16x16x32_bf16(
            qf[mi], kf[nj], acc[mi][nj], 0, 0, 0);
    __syncthreads();
  }
  float* pp = part + (size_t)(blockIdx.x * 4 + wid) * (HD * HD);
#pragma unroll
  for (int mi = 0; mi < 3; ++mi)
#pragma unroll
    for (int nj = 0; nj < 3; ++nj) {
      int kj = nj * 16 + (lane & 15);
#pragma unroll
      for (int rg = 0; rg < 4; ++rg) {
        int qi = mi * 16 + (lane >> 4) * 4 + rg;
        pp[qi * HD + kj] = acc[mi][nj][rg];
      }
    }
}

// ---------------------------------------------------------------------------
__global__ __launch_bounds__(64) void normred_kernel(
    const float* __restrict__ ssp, float* __restrict__ norms) {
  int idx = blockIdx.x;                 // 768 = 8 bh x 96 ch
  int bh = idx / 96, ch = idx % 96;
  int b = bh >> 2, hh = bh & 3;
  int l = threadIdx.x;
  float s = (l < 32) ? ssp[(size_t)bh * 96 * 32 + ch * 32 + l] : 0.f;
#pragma unroll
  for (int off = 32; off; off >>= 1) s += __shfl_down(s, off);
  if (l == 0) {
    int g = b * C2 + (ch < HD ? hh * HD + ch : CDIM + hh * HD + ch - HD);
    norms[g] = sqrtf(s);
  }
}

__global__ __launch_bounds__(256) void gramred_kernel(
    const float* __restrict__ part, float* __restrict__ logits) {
  int ij = blockIdx.x * 256 + threadIdx.x;
  int bh = blockIdx.y;
  if (ij >= HD * HD) return;
  const float* pp = part + (size_t)bh * 128 * (HD * HD);
  float s = 0.f;
  for (int sp = 0; sp < 128; ++sp) s += pp[(size_t)sp * (HD * HD) + ij];
  logits[(size_t)bh * (HD * HD) + ij] = s;
}

// ---------------------------------------------------------------------------
__global__ __launch_bounds__(64) void softmax_kernel(
    float* __restrict__ logits, const float* __restrict__ norms,
    const float* __restrict__ temperature) {
  int hh = blockIdx.x, b = blockIdx.y;
  int i = threadIdx.x;
  if (i >= HD) return;
  const float eps = 1e-12f;
  float temp = temperature[hh];
  float nq = fmaxf(norms[b * C2 + HD * hh + i], eps);
  float* row = logits + (((size_t)b * HEADS + hh) * HD + i) * HD;
  float vals[48];
  float mx = -1e30f;
#pragma unroll
  for (int j = 0; j < HD; ++j) {
    float nk = fmaxf(norms[b * C2 + CDIM + HD * hh + j], eps);
    float v = row[j] / (nq * nk) * temp;
    vals[j] = v;
    mx = fmaxf(mx, v);
  }
  float sum = 0.f;
#pragma unroll
  for (int j = 0; j < HD; ++j) {
    vals[j] = expf(vals[j] - mx);
    sum += vals[j];
  }
  float inv = 1.f / sum;
#pragma unroll
  for (int j = 0; j < HD; ++j) row[j] = vals[j] * inv;
}

// ---------------------------------------------------------------------------
__global__ __launch_bounds__(256) void buildM_kernel(
    const float* __restrict__ attn, const float* __restrict__ projw,
    float* __restrict__ M) {
  int idx = blockIdx.x * 256 + threadIdx.x;
  if (idx >= 2 * CDIM * CDIM) return;
  int d = idx % CDIM;
  int oc = (idx / CDIM) % CDIM;
  int b = idx / (CDIM * CDIM);
  int hh = d / HD, dd = d % HD;
  const float* arow = attn + ((size_t)b * HEADS + hh) * HD * HD;
  float s = 0.f;
#pragma unroll
  for (int c = 0; c < HD; ++c)
    s += projw[oc * CDIM + HD * hh + c] * arow[c * HD + dd];
  M[idx] = s;
}

// ---------------------------------------------------------------------------
// Wb[b][tap][oc][ic] (bf16) = sum_d M[b][oc][d] * Wv[d][ic][tap]
// ---------------------------------------------------------------------------
__global__ __launch_bounds__(256) void wtrans_kernel(
    const float* __restrict__ M, const float* __restrict__ Wv,
    unsigned short* __restrict__ Wb) {
  int oc = blockIdx.x;
  int b = blockIdx.y;
  const float* m = M + ((size_t)b * CDIM + oc) * CDIM;
  __shared__ float sM[CDIM];
  for (int i = threadIdx.x; i < CDIM; i += 256) sM[i] = m[i];
  __syncthreads();
  for (int e = threadIdx.x; e < CDIM * 9; e += 256) {
    int ic = e / 9, tap = e % 9;
    float s = 0.f;
    for (int d = 0; d < CDIM; ++d) s += sM[d] * Wv[(size_t)d * (CDIM * 9) + e];
    Wb[(((size_t)b * 9 + tap) * CDIM + oc) * CDIM + ic] = f2bf(s);
  }
}

// ---------------------------------------------------------------------------
// MFMA conv3x3 with XCD-aware remap: flat grid 1536 = 8 xcd * (64 pt * 3 oc).
// The 3 oc-tiles of a pixel tile + 64 neighboring pt share an XCD L2.
// ---------------------------------------------------------------------------
__global__ __launch_bounds__(256) void conv3x3_mfma_kernel(
    const unsigned short* __restrict__ Xt,   // [XTROWS][192] bf16 padded
    const unsigned short* __restrict__ Wb,   // [9][192][192] bf16
    float* __restrict__ out) {
  const int d = blockIdx.x;              // 1536
  const int xcd = d & 7;
  const int j = d >> 3;                  // 0..191
  const int pt = xcd * 64 + j / 3;       // 0..511
  const int oc0 = (j % 3) * 64;
  const int h = pt >> 1;
  const int w0 = (pt & 1) * 128;

  __shared__ short sA[64 * 32];
  __shared__ short sB[128 * 32];

  const int t = threadIdx.x;
  const int lane = t & 63;
  const int wid = t >> 6;
  const int wm = wid & 1;
  const int wn = wid >> 1;

  f32x4 acc[2][4];
#pragma unroll
  for (int mi = 0; mi < 2; ++mi)
#pragma unroll
    for (int ni = 0; ni < 4; ++ni) acc[mi][ni] = (f32x4){0.f, 0.f, 0.f, 0.f};

  const int lrow = lane >> 2;
  const int lcg  = (lane & 3) * 8;

  for (int tap = 0; tap < 9; ++tap) {
    const int r = tap / 3, c = tap % 3;
    const unsigned short* bsrc = Xt + ((size_t)(h + r) * PROW + w0 + c) * CDIM;
    const unsigned short* asrc = Wb + ((size_t)tap * CDIM + oc0) * CDIM;
    for (int ic0 = 0; ic0 < CDIM; ic0 += 32) {
      gload_lds16(asrc + (size_t)(wid * 16 + lrow) * CDIM + ic0 + lcg,
                  sA + wid * 16 * 32);
#pragma unroll
      for (int it = 0; it < 2; ++it) {
        int rb = it * 64 + wid * 16;
        gload_lds16(bsrc + (size_t)(rb + lrow) * CDIM + ic0 + lcg,
                    sB + rb * 32);
      }
      asm volatile("s_waitcnt vmcnt(0)");
      __syncthreads();
      short8 af[2], bf[4];
#pragma unroll
      for (int mi = 0; mi < 2; ++mi)
        af[mi] = *(const short8*)&sA[(wm * 32 + mi * 16 + (lane & 15)) * 32 +
                                     (lane >> 4) * 8];
#pragma unroll
      for (int ni = 0; ni < 4; ++ni)
        bf[ni] = *(const short8*)&sB[(wn * 64 + ni * 16 + (lane & 15)) * 32 +
                                     (lane >> 4) * 8];
#pragma unroll
      for (int mi = 0; mi < 2; ++mi)
#pragma unroll
        for (int ni = 0; ni < 4; ++ni)
          acc[mi][ni] = __builtin_amdgcn_mfma_f32_16x16x32_bf16(
              af[mi], bf[ni], acc[mi][ni], 0, 0, 0);
      __syncthreads();
    }
  }
#pragma unroll
  for (int mi = 0; mi < 2; ++mi) {
    int ocl = oc0 + wm * 32 + mi * 16 + (lane >> 4) * 4;
#pragma unroll
    for (int ni = 0; ni < 4; ++ni) {
      int wloc = w0 + wn * 64 + ni * 16 + (lane & 15);
#pragma unroll
      for (int rg = 0; rg < 4; ++rg)
        out[(size_t)(ocl + rg) * NPIX + h * 256 + wloc] = acc[mi][ni][rg];
    }
  }
}

// ---------------------------------------------------------------------------
extern "C" void kernel_launch(void* const* d_in, const int* in_sizes, int n_in,
                              void* d_out, int out_size, void* d_ws, size_t ws_size,
                              hipStream_t stream) {
  const float* x          = (const float*)d_in[0];
  const float* y          = (const float*)d_in[1];
  const float* qk_w       = (const float*)d_in[2];
  const float* qk_dw_w    = (const float*)d_in[3];
  const float* v_w        = (const float*)d_in[4];
  const float* v_dw_w     = (const float*)d_in[5];
  const float* proj_w     = (const float*)d_in[6];
  const float* temperature= (const float*)d_in[7];
  float* out = (float*)d_out;

  // Workspace layout. Peak ~75.6 MB (< 79.1 MB known-good).
  unsigned short* qkb = (unsigned short*)d_ws;          // [384][65536] bf16
  unsigned short* Xt  = qkb;                            // overlay (qkb dead)
  unsigned short* qkd = qkb + (size_t)C2 * NPIX;        // [96][65536] bf16
  float* ssp    = (float*)(qkd + (size_t)96 * NPIX);    // [8][96][32]
  float* gpart  = ssp + 8 * 96 * 32;                    // [8][128][2304]
  float* norms  = gpart + (size_t)8 * 128 * HD * HD;    // 768
  float* logits = norms + 768;                          // 4608
  float* M      = logits + 2 * HEADS * HD * HD;         // 73728
  unsigned short* wqk = (unsigned short*)(M + 2 * CDIM * CDIM);
  unsigned short* wv  = wqk + C2 * CDIM;
  unsigned short* Wb  = wv + CDIM * CDIM;               // 2*9*192*192 bf16
  size_t needB = (size_t)((char*)(Wb + (size_t)2 * 9 * CDIM * CDIM) - (char*)d_ws);
  if (ws_size < needB) return;

  castw_kernel<<<dim3(288), dim3(256), 0, stream>>>(qk_w, v_w, wqk, wv);

  // ---- qk path ----
  for (int b = 0; b < 2; ++b) {
    qk_mfma_kernel<<<dim3(1024), dim3(512), 0, stream>>>(
        x + (size_t)b * CDIM * NPIX, wqk, qkb);
    for (int h = 0; h < HEADS; ++h) {
      dwconv96_kernel<<<dim3(32, 96), dim3(256), 0, stream>>>(
          qkb, qk_dw_w, qkd, ssp + (size_t)(b * 4 + h) * 96 * 32,
          HD * h, CDIM + HD * h);
      gram_kernel<<<dim3(32), dim3(256), 0, stream>>>(
          qkd, gpart + (size_t)(b * 4 + h) * 128 * HD * HD);
    }
  }
  normred_kernel<<<dim3(768), dim3(64), 0, stream>>>(ssp, norms);
  gramred_kernel<<<dim3(9, 8), dim3(256), 0, stream>>>(gpart, logits);
  softmax_kernel<<<dim3(4, 2), dim3(64), 0, stream>>>(logits, norms, temperature);
  buildM_kernel<<<dim3(288), dim3(256), 0, stream>>>(logits, proj_w, M);
  wtrans_kernel<<<dim3(CDIM, 2), dim3(256), 0, stream>>>(M, v_dw_w, Wb);

  // ---- v path (Xt overlays qkb, now dead) ----
  for (int b = 0; b < 2; ++b) {
    hipMemsetAsync(Xt, 0, (size_t)XTROWS * CDIM * sizeof(unsigned short), stream);
    v_mfma_kernel<<<dim3(1024), dim3(256), 0, stream>>>(
        y + (size_t)b * CDIM * NPIX, wv, Xt);
    conv3x3_mfma_kernel<<<dim3(1536), dim3(256), 0, stream>>>(
        Xt, Wb + (size_t)b * 9 * CDIM * CDIM, out + (size_t)b * CDIM * NPIX);
  }
}

// Round 5
// 548.760 us; speedup vs baseline: 6.3959x; 1.0458x over previous
//
#include <hip/hip_runtime.h>
#include <hip/hip_bf16.h>

#define NPIX 65536
#define CDIM 192
#define C2   384
#define HEADS 4
#define HD   48
#define PROW 258                    // padded row length (256 + 2)
#define XTROWS (PROW * PROW)        // 66564 padded pixel rows

typedef float f32x4 __attribute__((ext_vector_type(4)));
typedef short short8 __attribute__((ext_vector_type(8)));

__device__ __forceinline__ unsigned short f2bf(float x) {
  union { float f; unsigned u; } v; v.f = x;
  unsigned r = v.u + 0x7fff + ((v.u >> 16) & 1);   // RNE
  return (unsigned short)(r >> 16);
}
__device__ __forceinline__ float bf2f(unsigned short x) {
  union { unsigned u; float f; } v; v.u = ((unsigned)x) << 16;
  return v.f;
}

__device__ __forceinline__ void gload_lds16(const void* g, void* l) {
  __builtin_amdgcn_global_load_lds(
      (const __attribute__((address_space(1))) unsigned int*)g,
      (__attribute__((address_space(3))) unsigned int*)l, 16, 0, 0);
}

// ---------------------------------------------------------------------------
// cast weights to bf16 once
// ---------------------------------------------------------------------------
__global__ __launch_bounds__(256) void castw_kernel(
    const float* __restrict__ qkw, const float* __restrict__ vw,
    unsigned short* __restrict__ wqk, unsigned short* __restrict__ wv) {
  int i = blockIdx.x * 256 + threadIdx.x;
  if (i < C2 * CDIM) wqk[i] = f2bf(qkw[i]);
  if (i < CDIM * CDIM) wv[i] = f2bf(vw[i]);
}

// ---------------------------------------------------------------------------
// qk 1x1 conv as MFMA GEMM: Out[oc][px] (bf16) = W[384][192] @ X[192][px].
// 512 thr (8 waves), tile M=384 (x read once), N=64 px, K=192.
// Epilogue: per-wave LDS bounce -> short8 coalesced stores.
// ---------------------------------------------------------------------------
__global__ __launch_bounds__(512) void qk_mfma_kernel(
    const float* __restrict__ X, const unsigned short* __restrict__ W,
    unsigned short* __restrict__ Out) {
  const int px0 = blockIdx.x * 64;
  __shared__ short sA[C2 * 32];    // 24576 B (reused as store zones)
  __shared__ short sB[64 * 40];    // 5120 B
  const int t = threadIdx.x;
  const int lane = t & 63;
  const int wid = t >> 6;          // 0..7 -> oc rows wid*48..+47
  const int cp = t & 15;           // channel pair
  const int pg = t >> 4;           // 0..31 -> px = 2pg

  f32x4 acc[3][4];
#pragma unroll
  for (int mi = 0; mi < 3; ++mi)
#pragma unroll
    for (int ni = 0; ni < 4; ++ni) acc[mi][ni] = (f32x4){0.f, 0.f, 0.f, 0.f};

  for (int k0 = 0; k0 < CDIM; k0 += 32) {
#pragma unroll
    for (int i = 0; i < 3; ++i) {
      int e = i * 512 + t;
      int oc = e >> 2, kg = e & 3;
      gload_lds16(W + (size_t)oc * CDIM + k0 + kg * 8,
                  (char*)sA + ((size_t)i * 512 + (t & ~63)) * 16);
    }
    {
      const float* xp = X + (size_t)(k0 + 2 * cp) * NPIX + px0 + 2 * pg;
      float2 a = *(const float2*)xp;
      float2 b = *(const float2*)(xp + NPIX);
      unsigned d0 = (unsigned)f2bf(a.x) | ((unsigned)f2bf(b.x) << 16);
      unsigned d1 = (unsigned)f2bf(a.y) | ((unsigned)f2bf(b.y) << 16);
      *(unsigned*)&sB[(2 * pg) * 40 + 2 * cp] = d0;
      *(unsigned*)&sB[(2 * pg + 1) * 40 + 2 * cp] = d1;
    }
    asm volatile("s_waitcnt vmcnt(0)");
    __syncthreads();
    short8 af[3], bf[4];
#pragma unroll
    for (int mi = 0; mi < 3; ++mi)
      af[mi] = *(const short8*)&sA[(wid * 48 + mi * 16 + (lane & 15)) * 32 +
                                   (lane >> 4) * 8];
#pragma unroll
    for (int ni = 0; ni < 4; ++ni)
      bf[ni] = *(const short8*)&sB[(ni * 16 + (lane & 15)) * 40 +
                                   (lane >> 4) * 8];
#pragma unroll
    for (int mi = 0; mi < 3; ++mi)
#pragma unroll
      for (int ni = 0; ni < 4; ++ni)
        acc[mi][ni] = __builtin_amdgcn_mfma_f32_16x16x32_bf16(
            af[mi], bf[ni], acc[mi][ni], 0, 0, 0);
    __syncthreads();
  }
  // Epilogue: per-wave zone (16 oc x 64 px, padded stride 72), short8 stores.
  __syncthreads();
  short* zone = sA + wid * 1152;     // 8 * 1152 = 9216 <= 12288 shorts
#pragma unroll
  for (int mi = 0; mi < 3; ++mi) {
#pragma unroll
    for (int ni = 0; ni < 4; ++ni)
#pragma unroll
      for (int rg = 0; rg < 4; ++rg)
        zone[((lane >> 4) * 4 + rg) * 72 + ni * 16 + (lane & 15)] =
            (short)f2bf(acc[mi][ni][rg]);
    asm volatile("s_waitcnt lgkmcnt(0)" ::: "memory");
    __builtin_amdgcn_sched_barrier(0);
#pragma unroll
    for (int it = 0; it < 2; ++it) {
      int e = it * 64 + lane;
      int ol = e >> 3, pxg = e & 7;
      short8 vv = *(const short8*)&zone[ol * 72 + pxg * 8];
      *(short8*)&Out[(size_t)(wid * 48 + mi * 16 + ol) * NPIX + px0 + pxg * 8] = vv;
    }
    asm volatile("s_waitcnt lgkmcnt(0)" ::: "memory");
    __builtin_amdgcn_sched_barrier(0);
  }
}

// ---------------------------------------------------------------------------
// v 1x1 conv as MFMA, output transposed into padded Xt (bf16) via LDS bounce.
// A = Y-pixels (m=px), B = weights (n=oc): D row=px, col=oc.
// ---------------------------------------------------------------------------
__global__ __launch_bounds__(256) void v_mfma_kernel(
    const float* __restrict__ Y, const unsigned short* __restrict__ W,
    unsigned short* __restrict__ Xt) {
  const int px0 = blockIdx.x * 64;
  const int h = px0 >> 8;
  const int w0 = px0 & 255;
  __shared__ short sX[64 * 40];    // 5120 B
  __shared__ short sW[CDIM * 32];  // 12288 B
  __shared__ short sZ[4 * 16 * 200];  // 25600 B store zones
  const int t = threadIdx.x;
  const int lane = t & 63;
  const int wid = t >> 6;
  const int cp = t & 15;
  const int pg = t >> 4;

  f32x4 acc[12];
#pragma unroll
  for (int ni = 0; ni < 12; ++ni) acc[ni] = (f32x4){0.f, 0.f, 0.f, 0.f};

  for (int k0 = 0; k0 < CDIM; k0 += 32) {
#pragma unroll
    for (int i = 0; i < 3; ++i) {
      int e = i * 256 + t;
      int oc = e >> 2, kg = e & 3;
      gload_lds16(W + (size_t)oc * CDIM + k0 + kg * 8,
                  (char*)sW + ((size_t)i * 256 + (t & ~63)) * 16);
    }
    {
      const float* xp = Y + (size_t)(k0 + 2 * cp) * NPIX + px0 + 4 * pg;
      float4 a = *(const float4*)xp;
      float4 b = *(const float4*)(xp + NPIX);
      float av[4] = {a.x, a.y, a.z, a.w};
      float bv[4] = {b.x, b.y, b.z, b.w};
#pragma unroll
      for (int i = 0; i < 4; ++i) {
        unsigned d = (unsigned)f2bf(av[i]) | ((unsigned)f2bf(bv[i]) << 16);
        *(unsigned*)&sX[(4 * pg + i) * 40 + 2 * cp] = d;
      }
    }
    asm volatile("s_waitcnt vmcnt(0)");
    __syncthreads();
    short8 af = *(const short8*)&sX[(wid * 16 + (lane & 15)) * 40 +
                                    (lane >> 4) * 8];
    short8 bf[12];
#pragma unroll
    for (int ni = 0; ni < 12; ++ni)
      bf[ni] = *(const short8*)&sW[(ni * 16 + (lane & 15)) * 32 +
                                   (lane >> 4) * 8];
#pragma unroll
    for (int ni = 0; ni < 12; ++ni)
      acc[ni] = __builtin_amdgcn_mfma_f32_16x16x32_bf16(af, bf[ni], acc[ni],
                                                        0, 0, 0);
    __syncthreads();
  }
  // Epilogue: zone [16 px][200 oc-pad], then short8 row stores into Xt.
  short* zone = sZ + wid * (16 * 200);
#pragma unroll
  for (int ni = 0; ni < 12; ++ni)
#pragma unroll
    for (int rg = 0; rg < 4; ++rg)
      zone[((lane >> 4) * 4 + rg) * 200 + ni * 16 + (lane & 15)] =
          (short)f2bf(acc[ni][rg]);
  asm volatile("s_waitcnt lgkmcnt(0)" ::: "memory");
  __builtin_amdgcn_sched_barrier(0);
#pragma unroll
  for (int it = 0; it < 6; ++it) {
    int e = it * 64 + lane;
    int pl = e / 24, cg = e % 24;
    short8 vv = *(const short8*)&zone[pl * 200 + cg * 8];
    size_t xrow = (size_t)(h + 1) * PROW + (w0 + wid * 16 + pl + 1);
    *(short8*)&Xt[xrow * CDIM + cg * 8] = vv;
  }
}

// ---------------------------------------------------------------------------
// Zero the padded border of Xt once (interior fully overwritten by v_mfma).
// ---------------------------------------------------------------------------
__global__ __launch_bounds__(128) void border_zero_kernel(
    unsigned short* __restrict__ Xt) {
  int pos = blockIdx.x;                 // 0..1027
  size_t row;
  if (pos < 258) row = pos;                                   // padded row 0
  else if (pos < 516) row = (size_t)257 * PROW + (pos - 258); // padded row 257
  else { int i = pos - 516; row = (size_t)(1 + (i >> 1)) * PROW + ((i & 1) ? 257 : 0); }
  unsigned* p = (unsigned*)(Xt + row * CDIM);
  if (threadIdx.x < 96) p[threadIdx.x] = 0;
}

// ---------------------------------------------------------------------------
// FUSED depthwise-3x3 + sumsq + Gram-MFMA for one (batch, head).
// Grid (128, 4heads) x 256 thr. Each wave: 128 px in 4 fills of 32 px.
// Per fill: compute dw(96ch x 32px) into per-wave LDS zone (bf16, padded 40),
// then 9 MFMAs (q rows 0-47 x k rows 48-95). Block-level reduce of 4 waves.
// ---------------------------------------------------------------------------
__global__ __launch_bounds__(256) void dwgram_kernel(
    const unsigned short* __restrict__ qkb, const float* __restrict__ dw,
    float* __restrict__ gpart_b, float* __restrict__ ssp_b) {
  const int head = blockIdx.y;
  const int blk = blockIdx.x;           // 0..127
  const int t = threadIdx.x;
  const int lane = t & 63;
  const int wid = t >> 6;

  __shared__ __align__(16) char smem[38400];
  short* zone = (short*)smem + wid * (96 * 40);   // 4 x 7680 B = 30720 B

  const int qrow0 = HD * head, krow0 = CDIM + HD * head;
  const int p0 = (lane & 1) * 16;       // px half within 32-chunk
  const int c0 = (lane >> 1) * 3;       // 3 channels per lane-pair

  float wr[3][9];
#pragma unroll
  for (int j = 0; j < 3; ++j) {
    int ch = c0 + j;
    int srow = (ch < HD) ? (qrow0 + ch) : (krow0 + ch - HD);
#pragma unroll
    for (int i = 0; i < 9; ++i) wr[j][i] = dw[srow * 9 + i];
  }

  f32x4 acc[3][3];
#pragma unroll
  for (int mi = 0; mi < 3; ++mi)
#pragma unroll
    for (int nj = 0; nj < 3; ++nj) acc[mi][nj] = (f32x4){0.f, 0.f, 0.f, 0.f};
  float ss[3] = {0.f, 0.f, 0.f};

  const int pxbase = blk * 512 + wid * 128;
  for (int s = 0; s < 4; ++s) {
    const int px0 = pxbase + s * 32;
    const int hr = px0 >> 8;
    const int col0 = px0 & 255;
    const int cl = col0 + p0;
#pragma unroll
    for (int j = 0; j < 3; ++j) {
      int ch = c0 + j;
      int srow = (ch < HD) ? (qrow0 + ch) : (krow0 + ch - HD);
      const unsigned short* ip = qkb + (size_t)srow * NPIX;
      float win[3][18];
#pragma unroll
      for (int r = 0; r < 3; ++r) {
        int ir = hr - 1 + r;
        if ((unsigned)ir < 256u) {
          const unsigned short* rp = ip + ir * 256 + cl;
          short8 v0 = *(const short8*)rp;
          short8 v1 = *(const short8*)(rp + 8);
#pragma unroll
          for (int q = 0; q < 8; ++q) {
            win[r][1 + q] = bf2f((unsigned short)v0[q]);
            win[r][9 + q] = bf2f((unsigned short)v1[q]);
          }
          win[r][0]  = (cl > 0)        ? bf2f(rp[-1]) : 0.f;
          win[r][17] = (cl + 16 < 256) ? bf2f(rp[16]) : 0.f;
        } else {
#pragma unroll
          for (int q = 0; q < 18; ++q) win[r][q] = 0.f;
        }
      }
      unsigned pk[8];
#pragma unroll
      for (int p = 0; p < 16; ++p) {
        float sacc = 0.f;
#pragma unroll
        for (int r = 0; r < 3; ++r)
#pragma unroll
          for (int c = 0; c < 3; ++c) sacc += wr[j][r * 3 + c] * win[r][p + c];
        ss[j] += sacc * sacc;
        unsigned short bb = f2bf(sacc);
        if (p & 1) pk[p >> 1] |= ((unsigned)bb << 16);
        else       pk[p >> 1] = bb;
      }
      unsigned* zp = (unsigned*)&zone[ch * 40 + p0];
#pragma unroll
      for (int q = 0; q < 8; ++q) zp[q] = pk[q];
    }
    asm volatile("s_waitcnt lgkmcnt(0)" ::: "memory");
    __builtin_amdgcn_sched_barrier(0);
    short8 qf[3], kf[3];
#pragma unroll
    for (int mi = 0; mi < 3; ++mi)
      qf[mi] = *(const short8*)&zone[(mi * 16 + (lane & 15)) * 40 +
                                     (lane >> 4) * 8];
#pragma unroll
    for (int nj = 0; nj < 3; ++nj)
      kf[nj] = *(const short8*)&zone[(HD + nj * 16 + (lane & 15)) * 40 +
                                     (lane >> 4) * 8];
#pragma unroll
    for (int mi = 0; mi < 3; ++mi)
#pragma unroll
      for (int nj = 0; nj < 3; ++nj)
        acc[mi][nj] = __builtin_amdgcn_mfma_f32_16x16x32_bf16(
            qf[mi], kf[nj], acc[mi][nj], 0, 0, 0);
    asm volatile("s_waitcnt lgkmcnt(0)" ::: "memory");
    __builtin_amdgcn_sched_barrier(0);
  }
  // ---- block-level reduce: zones dead, overlay reduction buffers ----
  __syncthreads();
  float* red   = (float*)smem;            // [4][2304]
  float* ssred = (float*)(smem + 36864);  // [4][96]
#pragma unroll
  for (int mi = 0; mi < 3; ++mi)
#pragma unroll
    for (int nj = 0; nj < 3; ++nj) {
      int kj = nj * 16 + (lane & 15);
#pragma unroll
      for (int rg = 0; rg < 4; ++rg) {
        int qi = mi * 16 + (lane >> 4) * 4 + rg;
        red[wid * 2304 + qi * HD + kj] = acc[mi][nj][rg];
      }
    }
#pragma unroll
  for (int j = 0; j < 3; ++j) {
    float sj = ss[j] + __shfl_xor(ss[j], 1);
    if ((lane & 1) == 0) ssred[wid * 96 + c0 + j] = sj;
  }
  __syncthreads();
  float* gp = gpart_b + (size_t)(head * 128 + blk) * (HD * HD);
  for (int e = t; e < HD * HD; e += 256)
    gp[e] = red[e] + red[2304 + e] + red[4608 + e] + red[6912 + e];
  if (t < 96)
    ssp_b[(size_t)(head * 128 + blk) * 96 + t] =
        ssred[t] + ssred[96 + t] + ssred[192 + t] + ssred[288 + t];
}

// ---------------------------------------------------------------------------
__global__ __launch_bounds__(128) void normred_kernel(
    const float* __restrict__ ssp, float* __restrict__ norms) {
  int idx = blockIdx.x;                 // 768 = 8 bh x 96 ch
  int bh = idx / 96, ch = idx % 96;
  int l = threadIdx.x;                  // 128
  float s = ssp[((size_t)bh * 128 + l) * 96 + ch];
#pragma unroll
  for (int off = 32; off; off >>= 1) s += __shfl_down(s, off);
  __shared__ float red[2];
  if ((l & 63) == 0) red[l >> 6] = s;
  __syncthreads();
  if (l == 0) {
    int b = bh >> 2, hh = bh & 3;
    int g = b * C2 + (ch < HD ? hh * HD + ch : CDIM + hh * HD + ch - HD);
    norms[g] = sqrtf(red[0] + red[1]);
  }
}

__global__ __launch_bounds__(256) void gramred_kernel(
    const float* __restrict__ part, float* __restrict__ logits) {
  int ij = blockIdx.x * 256 + threadIdx.x;
  int bh = blockIdx.y;
  if (ij >= HD * HD) return;
  const float* pp = part + (size_t)bh * 128 * (HD * HD);
  float s = 0.f;
  for (int sp = 0; sp < 128; ++sp) s += pp[(size_t)sp * (HD * HD) + ij];
  logits[(size_t)bh * (HD * HD) + ij] = s;
}

// ---------------------------------------------------------------------------
__global__ __launch_bounds__(64) void softmax_kernel(
    float* __restrict__ logits, const float* __restrict__ norms,
    const float* __restrict__ temperature) {
  int hh = blockIdx.x, b = blockIdx.y;
  int i = threadIdx.x;
  if (i >= HD) return;
  const float eps = 1e-12f;
  float temp = temperature[hh];
  float nq = fmaxf(norms[b * C2 + HD * hh + i], eps);
  float* row = logits + (((size_t)b * HEADS + hh) * HD + i) * HD;
  float vals[48];
  float mx = -1e30f;
#pragma unroll
  for (int j = 0; j < HD; ++j) {
    float nk = fmaxf(norms[b * C2 + CDIM + HD * hh + j], eps);
    float v = row[j] / (nq * nk) * temp;
    vals[j] = v;
    mx = fmaxf(mx, v);
  }
  float sum = 0.f;
#pragma unroll
  for (int j = 0; j < HD; ++j) {
    vals[j] = expf(vals[j] - mx);
    sum += vals[j];
  }
  float inv = 1.f / sum;
#pragma unroll
  for (int j = 0; j < HD; ++j) row[j] = vals[j] * inv;
}

// ---------------------------------------------------------------------------
__global__ __launch_bounds__(256) void buildM_kernel(
    const float* __restrict__ attn, const float* __restrict__ projw,
    float* __restrict__ M) {
  int idx = blockIdx.x * 256 + threadIdx.x;
  if (idx >= 2 * CDIM * CDIM) return;
  int d = idx % CDIM;
  int oc = (idx / CDIM) % CDIM;
  int b = idx / (CDIM * CDIM);
  int hh = d / HD, dd = d % HD;
  const float* arow = attn + ((size_t)b * HEADS + hh) * HD * HD;
  float s = 0.f;
#pragma unroll
  for (int c = 0; c < HD; ++c)
    s += projw[oc * CDIM + HD * hh + c] * arow[c * HD + dd];
  M[idx] = s;
}

// ---------------------------------------------------------------------------
// Wb[b][tap][oc][ic] (bf16) = sum_d M[b][oc][d] * Wv[d][ic][tap]
// Grid (48, 2): 4 oc per block; Wv streamed once per block, coalesced.
// ---------------------------------------------------------------------------
__global__ __launch_bounds__(256) void wtrans_kernel(
    const float* __restrict__ M, const float* __restrict__ Wv,
    unsigned short* __restrict__ Wb) {
  int ocb = blockIdx.x * 4;
  int b = blockIdx.y;
  __shared__ float sM[4][CDIM];
  for (int i = threadIdx.x; i < 4 * CDIM; i += 256)
    sM[i / CDIM][i % CDIM] =
        M[((size_t)b * CDIM + ocb + i / CDIM) * CDIM + (i % CDIM)];
  __syncthreads();
  for (int e = threadIdx.x; e < CDIM * 9; e += 256) {
    float a0 = 0.f, a1 = 0.f, a2 = 0.f, a3 = 0.f;
    for (int d = 0; d < CDIM; ++d) {
      float wv = Wv[(size_t)d * (CDIM * 9) + e];
      a0 += sM[0][d] * wv; a1 += sM[1][d] * wv;
      a2 += sM[2][d] * wv; a3 += sM[3][d] * wv;
    }
    int ic = e / 9, tap = e % 9;
    size_t base = (((size_t)b * 9 + tap) * CDIM) * CDIM + ic;
    Wb[base + (size_t)(ocb + 0) * CDIM] = f2bf(a0);
    Wb[base + (size_t)(ocb + 1) * CDIM] = f2bf(a1);
    Wb[base + (size_t)(ocb + 2) * CDIM] = f2bf(a2);
    Wb[base + (size_t)(ocb + 3) * CDIM] = f2bf(a3);
  }
}

// ---------------------------------------------------------------------------
// MFMA conv3x3 v2: one B-stage per tap-row r (sB[130 px rows][200-short pad],
// bank-clean 400B stride), A-fragments direct from L2, 3 barrier-pairs total.
// XCD-aware remap kept. 64 oc x 128 px per block.
// ---------------------------------------------------------------------------
__global__ __launch_bounds__(256) void conv3x3_mfma_kernel(
    const unsigned short* __restrict__ Xt,   // [XTROWS][192] bf16 padded
    const unsigned short* __restrict__ Wb,   // [9][192][192] bf16
    float* __restrict__ out) {
  const int d = blockIdx.x;              // 1536
  const int xcd = d & 7;
  const int j = d >> 3;                  // 0..191
  const int pt = xcd * 64 + j / 3;       // 0..511
  const int oc0 = (j % 3) * 64;
  const int h = pt >> 1;
  const int w0 = (pt & 1) * 128;

  __shared__ short sB[3328 * 8];         // 53248 B (130 rows x 25 chunks + slack)

  const int t = threadIdx.x;
  const int lane = t & 63;
  const int wid = t >> 6;
  const int wm = wid & 1;                // oc half (32)
  const int wn = wid >> 1;               // px half (64)

  f32x4 acc[2][4];
#pragma unroll
  for (int mi = 0; mi < 2; ++mi)
#pragma unroll
    for (int ni = 0; ni < 4; ++ni) acc[mi][ni] = (f32x4){0.f, 0.f, 0.f, 0.f};

#define STAGE_B(rr)                                                          \
  {                                                                          \
    const unsigned short* bsrc =                                             \
        Xt + ((size_t)(h + (rr)) * PROW + w0) * CDIM;                        \
    _Pragma("unroll")                                                        \
    for (int i = 0; i < 13; ++i) {                                           \
      int g = i * 256 + t;                                                   \
      if (g < 3250) {                                                        \
        int row = g / 25, cc = g % 25;                                       \
        gload_lds16(bsrc + (size_t)row * CDIM + (cc == 24 ? 0 : cc * 8),     \
                    sB + (size_t)(i * 256 + (t & ~63)) * 8);                 \
      }                                                                      \
    }                                                                        \
  }

  STAGE_B(0);
  asm volatile("s_waitcnt vmcnt(0)");
  __syncthreads();

  for (int r = 0; r < 3; ++r) {
#pragma unroll
    for (int c = 0; c < 3; ++c) {
      const unsigned short* asrc = Wb + ((size_t)(r * 3 + c) * CDIM + oc0) * CDIM;
      short8 afl[12];
#pragma unroll
      for (int kk = 0; kk < 6; ++kk)
#pragma unroll
        for (int mi = 0; mi < 2; ++mi)
          afl[kk * 2 + mi] = *(const short8*)&asrc[
              (size_t)(wm * 32 + mi * 16 + (lane & 15)) * CDIM + kk * 32 +
              (lane >> 4) * 8];
#pragma unroll
      for (int kk = 0; kk < 6; ++kk) {
        short8 bfl[4];
#pragma unroll
        for (int ni = 0; ni < 4; ++ni)
          bfl[ni] = *(const short8*)&sB[
              (size_t)(wn * 64 + ni * 16 + (lane & 15) + c) * 200 + kk * 32 +
              (lane >> 4) * 8];
#pragma unroll
        for (int mi = 0; mi < 2; ++mi)
#pragma unroll
          for (int ni = 0; ni < 4; ++ni)
            acc[mi][ni] = __builtin_amdgcn_mfma_f32_16x16x32_bf16(
                afl[kk * 2 + mi], bfl[ni], acc[mi][ni], 0, 0, 0);
      }
    }
    if (r < 2) {
      __syncthreads();
      STAGE_B(r + 1);
      asm volatile("s_waitcnt vmcnt(0)");
      __syncthreads();
    }
  }
#undef STAGE_B
#pragma unroll
  for (int mi = 0; mi < 2; ++mi) {
    int ocl = oc0 + wm * 32 + mi * 16 + (lane >> 4) * 4;
#pragma unroll
    for (int ni = 0; ni < 4; ++ni) {
      int wloc = w0 + wn * 64 + ni * 16 + (lane & 15);
#pragma unroll
      for (int rg = 0; rg < 4; ++rg)
        out[(size_t)(ocl + rg) * NPIX + h * 256 + wloc] = acc[mi][ni][rg];
    }
  }
}

// ---------------------------------------------------------------------------
extern "C" void kernel_launch(void* const* d_in, const int* in_sizes, int n_in,
                              void* d_out, int out_size, void* d_ws, size_t ws_size,
                              hipStream_t stream) {
  const float* x          = (const float*)d_in[0];
  const float* y          = (const float*)d_in[1];
  const float* qk_w       = (const float*)d_in[2];
  const float* qk_dw_w    = (const float*)d_in[3];
  const float* v_w        = (const float*)d_in[4];
  const float* v_dw_w     = (const float*)d_in[5];
  const float* proj_w     = (const float*)d_in[6];
  const float* temperature= (const float*)d_in[7];
  float* out = (float*)d_out;

  // Workspace layout. Peak ~62 MB.
  unsigned short* qkb = (unsigned short*)d_ws;          // [384][65536] bf16 (50.3 MB)
  unsigned short* Xt  = qkb;                            // overlay (qkb dead in v path)
  float* gpart  = (float*)(qkb + (size_t)C2 * NPIX);    // [8][128][2304] (9.4 MB)
  float* ssp    = gpart + (size_t)8 * 128 * HD * HD;    // [8][128][96]
  float* norms  = ssp + (size_t)8 * 128 * 96;           // 768
  float* logits = norms + 768;                          // 4608
  float* M      = logits + 2 * HEADS * HD * HD;         // 73728
  unsigned short* wqk = (unsigned short*)(M + 2 * CDIM * CDIM);
  unsigned short* wv  = wqk + C2 * CDIM;
  unsigned short* Wb  = wv + CDIM * CDIM;               // 2*9*192*192 bf16
  size_t needB = (size_t)((char*)(Wb + (size_t)2 * 9 * CDIM * CDIM) - (char*)d_ws);
  if (ws_size < needB) return;

  castw_kernel<<<dim3(288), dim3(256), 0, stream>>>(qk_w, v_w, wqk, wv);

  // ---- qk path: full-M 1x1 MFMA, then fused dw+sumsq+gram per batch ----
  for (int b = 0; b < 2; ++b) {
    qk_mfma_kernel<<<dim3(1024), dim3(512), 0, stream>>>(
        x + (size_t)b * CDIM * NPIX, wqk, qkb);
    dwgram_kernel<<<dim3(128, HEADS), dim3(256), 0, stream>>>(
        qkb, qk_dw_w,
        gpart + (size_t)b * HEADS * 128 * HD * HD,
        ssp + (size_t)b * HEADS * 128 * 96);
  }
  normred_kernel<<<dim3(768), dim3(128), 0, stream>>>(ssp, norms);
  gramred_kernel<<<dim3(9, 8), dim3(256), 0, stream>>>(gpart, logits);
  softmax_kernel<<<dim3(4, 2), dim3(64), 0, stream>>>(logits, norms, temperature);
  buildM_kernel<<<dim3(288), dim3(256), 0, stream>>>(logits, proj_w, M);
  wtrans_kernel<<<dim3(48, 2), dim3(256), 0, stream>>>(M, v_dw_w, Wb);

  // ---- v path (Xt overlays qkb, now dead) ----
  border_zero_kernel<<<dim3(1028), dim3(128), 0, stream>>>(Xt);
  for (int b = 0; b < 2; ++b) {
    v_mfma_kernel<<<dim3(1024), dim3(256), 0, stream>>>(
        y + (size_t)b * CDIM * NPIX, wv, Xt);
    conv3x3_mfma_kernel<<<dim3(1536), dim3(256), 0, stream>>>(
        Xt, Wb + (size_t)b * 9 * CDIM * CDIM, out + (size_t)b * CDIM * NPIX);
  }
}